// Round 21
// baseline (3126.156 us; speedup 1.0000x reference)
//
#include <hip/hip_runtime.h>
#include <math.h>
#include <stdint.h>

constexpr int T_STEPS = 32;
constexpr int BATCH   = 128;
constexpr int IN_SZ   = 2048;   // K
constexpr int OUT_SZ  = 2048;   // N

// -------------------------------------------------------------------------
// FROZEN reference arithmetic (verified r14, absmax 0.0 r15-r20):
//   GEMM: f32, KC=512 uniform K-blocks; per element a fresh ascending-k
//         fmaf chain per block, f32 sequential block-combine.
//   Scan: f64 state, un = D*u + y (sep mul/add), s = (un>=1), u = un-s,
//         D = 1/(1+exp(-2)) in f64.
// r21 = r19's exact inline structure (128x64 tile, 8x4 micro, B staged via
// zero-VGPR global_load_lds DMA, A reg-prefetched, double-buffered, ONE
// barrier per K-step) with the register pathologies fixed:
//   - __launch_bounds__(256,3): r19's (256,4) forced VGPR=64 -> spill
//   - NO lambdas around register arrays: r20's kstep lambda made acc/su
//     address-taken -> scratch (9 GB of WRITE traffic)
// Per-element chain arithmetic bit-identical to r15-r20.
// -------------------------------------------------------------------------

__device__ __forceinline__ void async_lds16(const float* gsrc, float* lds_dst) {
    __builtin_amdgcn_global_load_lds(
        (const __attribute__((address_space(1))) uint32_t*)(uintptr_t)gsrc,
        (__attribute__((address_space(3))) uint32_t*)(uint32_t)(uintptr_t)lds_dst,
        16, 0, 0);
}

__global__ __launch_bounds__(256, 3) void Approx_OTPE_67181878444197_kernel(
        const float* __restrict__ x,
        const float* __restrict__ W,
        float* __restrict__ out) {
    constexpr int BK = 16, BM = 128, BN = 64;
    constexpr int ASZ  = BK * BM;          // 2048 floats
    constexpr int BSZ  = BK * BN;          // 1024 floats
    constexpr int BUF  = ASZ + BSZ;        // 3072 floats per stage buffer
    constexpr int YSTR = BN + 1;           // 65
    constexpr int YSZ  = BM * YSTR;        // 8320 floats = 33.3 KB
    constexpr int NIT  = IN_SZ / BK;       // 128

    __shared__ float smem[YSZ];            // y-buffer aliases both stage bufs

    const int o0  = blockIdx.x * BN;
    const int b0  = blockIdx.y * 4;
    const int tid = threadIdx.x;           // 0..255
    const int ty  = tid >> 4;              // 0..15 -> 8-row group
    const int tx  = tid & 15;              // 0..15 -> 4-col group
    const int wv  = tid >> 6;              // wave id 0..3 (wave-uniform)

    // A staging: m_local = tid>>1 (0..127), k-half = (tid&1)*8
    const int am = tid >> 1;
    const int ak = (tid & 1) * 8;
    const int at = am >> 2;
    const int ab = am & 3;
    const size_t aBase = ((size_t)at * BATCH + (size_t)(b0 + ab)) * IN_SZ + ak;

    // B staging (DMA): lane-linear [k][n] tile; row br, col bc
    const int br = tid >> 4;
    const int bc = (tid & 15) * 4;

    float acc[8][4] = {};   // current KC=512 chain
    float su[8][4]  = {};   // running sequential block-combine

    // ---- prologue: stage tile 0 into buffer 0 ---------------------------
    {
        float* const A0 = smem;
        async_lds16(&W[(size_t)br * OUT_SZ + o0 + bc], smem + ASZ + wv * 256);
        const float4 a0 = *reinterpret_cast<const float4*>(&x[aBase + 0]);
        const float4 a1 = *reinterpret_cast<const float4*>(&x[aBase + 4]);
        A0[(ak + 0) * BM + am] = a0.x;
        A0[(ak + 1) * BM + am] = a0.y;
        A0[(ak + 2) * BM + am] = a0.z;
        A0[(ak + 3) * BM + am] = a0.w;
        A0[(ak + 4) * BM + am] = a1.x;
        A0[(ak + 5) * BM + am] = a1.y;
        A0[(ak + 6) * BM + am] = a1.z;
        A0[(ak + 7) * BM + am] = a1.w;
    }
    __syncthreads();   // drains the DMA (vmcnt 0) + A writes

    // ---- main loop: ONE barrier per K-step (inline, no lambdas) ---------
    #pragma unroll 1
    for (int it = 0; it < NIT; ++it) {
        const float* const Ac = smem + (it & 1) * BUF;
        const float* const Bc = Ac + ASZ;
        float* const An = smem + ((it + 1) & 1) * BUF;

        // issue next tile's staging FIRST: B as zero-reg DMA, A into regs
        float4 pa0, pa1;
        const bool pre = (it < NIT - 1);
        if (pre) {
            const int k0n = (it + 1) * BK;
            async_lds16(&W[(size_t)(k0n + br) * OUT_SZ + o0 + bc],
                        An + ASZ + wv * 256);
            pa0 = *reinterpret_cast<const float4*>(&x[aBase + k0n]);
            pa1 = *reinterpret_cast<const float4*>(&x[aBase + k0n + 4]);
        }

        // KC=512 boundary (k0 = 512/1024/1536): sequential combine
        if (it == 32 || it == 64 || it == 96) {
            #pragma unroll
            for (int i = 0; i < 8; ++i)
                #pragma unroll
                for (int j = 0; j < 4; ++j) {
                    su[i][j]  = __fadd_rn(su[i][j], acc[i][j]);
                    acc[i][j] = 0.0f;
                }
        }

        // ascending k; each acc[i][j] is one strict fmaf chain
        #pragma unroll
        for (int k = 0; k < BK; ++k) {
            const float4 x0 = *reinterpret_cast<const float4*>(&Ac[k * BM + ty * 8]);
            const float4 x1 = *reinterpret_cast<const float4*>(&Ac[k * BM + ty * 8 + 4]);
            const float4 wf = *reinterpret_cast<const float4*>(&Bc[k * BN + tx * 4]);
            const float a[8] = {x0.x, x0.y, x0.z, x0.w, x1.x, x1.y, x1.z, x1.w};
            const float w[4] = {wf.x, wf.y, wf.z, wf.w};
            #pragma unroll
            for (int i = 0; i < 8; ++i)
                #pragma unroll
                for (int j = 0; j < 4; ++j)
                    acc[i][j] = __builtin_fmaf(a[i], w[j], acc[i][j]);
        }

        // write prefetched A into the other buffer (latency was hidden)
        if (pre) {
            An[(ak + 0) * BM + am] = pa0.x;
            An[(ak + 1) * BM + am] = pa0.y;
            An[(ak + 2) * BM + am] = pa0.z;
            An[(ak + 3) * BM + am] = pa0.w;
            An[(ak + 4) * BM + am] = pa1.x;
            An[(ak + 5) * BM + am] = pa1.y;
            An[(ak + 6) * BM + am] = pa1.z;
            An[(ak + 7) * BM + am] = pa1.w;
        }
        __syncthreads();   // implicit vmcnt(0): next tile's DMA complete
    }

    // final combine (frozen) + y-transpose dump (staging region is dead)
    #pragma unroll
    for (int i = 0; i < 8; ++i)
        #pragma unroll
        for (int j = 0; j < 4; ++j)
            smem[(ty * 8 + i) * YSTR + tx * 4 + j] = __fadd_rn(su[i][j], acc[i][j]);
    __syncthreads();

    // fused f64 scan: all 256 threads, one (bl, o) pair each
    {
        const int bl = tid >> 6;            // 0..3
        const int o  = tid & 63;            // 0..63
        const size_t plane  = (size_t)BATCH * OUT_SZ;
        const size_t outIdx = (size_t)(b0 + bl) * OUT_SZ + o0 + o;

        const double D = 1.0 / (1.0 + exp(-2.0));
        double u = 0.0;
        #pragma unroll
        for (int t = 0; t < T_STEPS; ++t) {
            const double y  = (double)smem[(t * 4 + bl) * YSTR + o];
            const double un = __dadd_rn(__dmul_rn(D, u), y);
            const double s  = (un >= 1.0) ? 1.0 : 0.0;
            u = __dsub_rn(un, s);
            out[(size_t)t * plane + outIdx] = (float)s;
        }
    }
}

// -------------------------------------------------------------------------
extern "C" void kernel_launch(void* const* d_in, const int* in_sizes, int n_in,
                              void* d_out, int out_size, void* d_ws, size_t ws_size,
                              hipStream_t stream) {
    const float* x = (const float*)d_in[0];   // [T, B, IN] f32
    const float* W = (const float*)d_in[1];   // [IN, OUT] f32
    float* out     = (float*)d_out;           // [T, B, OUT] f32 spikes

    dim3 grid(OUT_SZ / 64, BATCH / 4);        // 32 x 32 = 1024 blocks (4/CU)
    Approx_OTPE_67181878444197_kernel<<<grid, 256, 0, stream>>>(x, W, out);
}

// Round 22
// 722.108 us; speedup vs baseline: 4.3292x; 4.3292x over previous
//
#include <hip/hip_runtime.h>
#include <math.h>
#include <stdint.h>

constexpr int T_STEPS = 32;
constexpr int BATCH   = 128;
constexpr int IN_SZ   = 2048;   // K
constexpr int OUT_SZ  = 2048;   // N

// -------------------------------------------------------------------------
// FROZEN reference arithmetic (verified r14, absmax 0.0 r15-r21):
//   GEMM: f32, KC=512 uniform K-blocks; per element a fresh ascending-k
//         fmaf chain per block, f32 sequential block-combine.
//   Scan: f64 state, un = D*u + y (sep mul/add), s = (un>=1), u = un-s,
//         D = 1/(1+exp(-2)) in f64.
// r22 = r19's pipeline with the allocator unhandicapped:
//   __launch_bounds__(256) ONLY. Evidence: (256,1) never spilled (r16: 80
//   VGPR, r18: 148); (256,4) forced 64+spill (r19); (256,3) caused a
//   scratch catastrophe regardless of lambdas (r20/r21).
// Structure: 128x64 tile, 8x4 micro, B staged via zero-VGPR global_load_lds
// DMA, A reg-prefetched, double-buffered LDS, ONE barrier per K-step.
// Per-element chain arithmetic bit-identical to r15-r21.
// -------------------------------------------------------------------------

__device__ __forceinline__ void async_lds16(const float* gsrc, float* lds_dst) {
    __builtin_amdgcn_global_load_lds(
        (const __attribute__((address_space(1))) uint32_t*)(uintptr_t)gsrc,
        (__attribute__((address_space(3))) uint32_t*)(uint32_t)(uintptr_t)lds_dst,
        16, 0, 0);
}

__global__ __launch_bounds__(256) void Approx_OTPE_67181878444197_kernel(
        const float* __restrict__ x,
        const float* __restrict__ W,
        float* __restrict__ out) {
    constexpr int BK = 16, BM = 128, BN = 64;
    constexpr int ASZ  = BK * BM;          // 2048 floats
    constexpr int BSZ  = BK * BN;          // 1024 floats
    constexpr int BUF  = ASZ + BSZ;        // 3072 floats per stage buffer
    constexpr int YSTR = BN + 1;           // 65
    constexpr int YSZ  = BM * YSTR;        // 8320 floats = 33.3 KB
    constexpr int NIT  = IN_SZ / BK;       // 128

    __shared__ float smem[YSZ];            // y-buffer aliases both stage bufs

    const int o0  = blockIdx.x * BN;
    const int b0  = blockIdx.y * 4;
    const int tid = threadIdx.x;           // 0..255
    const int ty  = tid >> 4;              // 0..15 -> 8-row group
    const int tx  = tid & 15;              // 0..15 -> 4-col group
    const int wv  = tid >> 6;              // wave id 0..3 (wave-uniform)

    // A staging: m_local = tid>>1 (0..127), k-half = (tid&1)*8
    const int am = tid >> 1;
    const int ak = (tid & 1) * 8;
    const int at = am >> 2;
    const int ab = am & 3;
    const size_t aBase = ((size_t)at * BATCH + (size_t)(b0 + ab)) * IN_SZ + ak;

    // B staging (DMA): lane-linear [k][n] tile; row br, col bc
    const int br = tid >> 4;
    const int bc = (tid & 15) * 4;

    float acc[8][4] = {};   // current KC=512 chain
    float su[8][4]  = {};   // running sequential block-combine

    // ---- prologue: stage tile 0 into buffer 0 ---------------------------
    {
        float* const A0 = smem;
        async_lds16(&W[(size_t)br * OUT_SZ + o0 + bc], smem + ASZ + wv * 256);
        const float4 a0 = *reinterpret_cast<const float4*>(&x[aBase + 0]);
        const float4 a1 = *reinterpret_cast<const float4*>(&x[aBase + 4]);
        A0[(ak + 0) * BM + am] = a0.x;
        A0[(ak + 1) * BM + am] = a0.y;
        A0[(ak + 2) * BM + am] = a0.z;
        A0[(ak + 3) * BM + am] = a0.w;
        A0[(ak + 4) * BM + am] = a1.x;
        A0[(ak + 5) * BM + am] = a1.y;
        A0[(ak + 6) * BM + am] = a1.z;
        A0[(ak + 7) * BM + am] = a1.w;
    }
    __syncthreads();   // drains the DMA (vmcnt 0) + A writes

    // ---- main loop: ONE barrier per K-step (inline) ---------------------
    #pragma unroll 1
    for (int it = 0; it < NIT; ++it) {
        const float* const Ac = smem + (it & 1) * BUF;
        const float* const Bc = Ac + ASZ;
        float* const An = smem + ((it + 1) & 1) * BUF;

        // issue next tile's staging FIRST: B as zero-reg DMA, A into regs
        float4 pa0, pa1;
        const bool pre = (it < NIT - 1);
        if (pre) {
            const int k0n = (it + 1) * BK;
            async_lds16(&W[(size_t)(k0n + br) * OUT_SZ + o0 + bc],
                        An + ASZ + wv * 256);
            pa0 = *reinterpret_cast<const float4*>(&x[aBase + k0n]);
            pa1 = *reinterpret_cast<const float4*>(&x[aBase + k0n + 4]);
        }

        // KC=512 boundary (k0 = 512/1024/1536): sequential combine
        if (it == 32 || it == 64 || it == 96) {
            #pragma unroll
            for (int i = 0; i < 8; ++i)
                #pragma unroll
                for (int j = 0; j < 4; ++j) {
                    su[i][j]  = __fadd_rn(su[i][j], acc[i][j]);
                    acc[i][j] = 0.0f;
                }
        }

        // ascending k; each acc[i][j] is one strict fmaf chain
        #pragma unroll
        for (int k = 0; k < BK; ++k) {
            const float4 x0 = *reinterpret_cast<const float4*>(&Ac[k * BM + ty * 8]);
            const float4 x1 = *reinterpret_cast<const float4*>(&Ac[k * BM + ty * 8 + 4]);
            const float4 wf = *reinterpret_cast<const float4*>(&Bc[k * BN + tx * 4]);
            const float a[8] = {x0.x, x0.y, x0.z, x0.w, x1.x, x1.y, x1.z, x1.w};
            const float w[4] = {wf.x, wf.y, wf.z, wf.w};
            #pragma unroll
            for (int i = 0; i < 8; ++i)
                #pragma unroll
                for (int j = 0; j < 4; ++j)
                    acc[i][j] = __builtin_fmaf(a[i], w[j], acc[i][j]);
        }

        // write prefetched A into the other buffer (latency was hidden)
        if (pre) {
            An[(ak + 0) * BM + am] = pa0.x;
            An[(ak + 1) * BM + am] = pa0.y;
            An[(ak + 2) * BM + am] = pa0.z;
            An[(ak + 3) * BM + am] = pa0.w;
            An[(ak + 4) * BM + am] = pa1.x;
            An[(ak + 5) * BM + am] = pa1.y;
            An[(ak + 6) * BM + am] = pa1.z;
            An[(ak + 7) * BM + am] = pa1.w;
        }
        __syncthreads();   // implicit vmcnt(0): next tile's DMA complete
    }

    // final combine (frozen) + y-transpose dump (staging region is dead)
    #pragma unroll
    for (int i = 0; i < 8; ++i)
        #pragma unroll
        for (int j = 0; j < 4; ++j)
            smem[(ty * 8 + i) * YSTR + tx * 4 + j] = __fadd_rn(su[i][j], acc[i][j]);
    __syncthreads();

    // fused f64 scan: all 256 threads, one (bl, o) pair each
    {
        const int bl = tid >> 6;            // 0..3
        const int o  = tid & 63;            // 0..63
        const size_t plane  = (size_t)BATCH * OUT_SZ;
        const size_t outIdx = (size_t)(b0 + bl) * OUT_SZ + o0 + o;

        const double D = 1.0 / (1.0 + exp(-2.0));
        double u = 0.0;
        #pragma unroll
        for (int t = 0; t < T_STEPS; ++t) {
            const double y  = (double)smem[(t * 4 + bl) * YSTR + o];
            const double un = __dadd_rn(__dmul_rn(D, u), y);
            const double s  = (un >= 1.0) ? 1.0 : 0.0;
            u = __dsub_rn(un, s);
            out[(size_t)t * plane + outIdx] = (float)s;
        }
    }
}

// -------------------------------------------------------------------------
extern "C" void kernel_launch(void* const* d_in, const int* in_sizes, int n_in,
                              void* d_out, int out_size, void* d_ws, size_t ws_size,
                              hipStream_t stream) {
    const float* x = (const float*)d_in[0];   // [T, B, IN] f32
    const float* W = (const float*)d_in[1];   // [IN, OUT] f32
    float* out     = (float*)d_out;           // [T, B, OUT] f32 spikes

    dim3 grid(OUT_SZ / 64, BATCH / 4);        // 32 x 32 = 1024 blocks
    Approx_OTPE_67181878444197_kernel<<<grid, 256, 0, stream>>>(x, W, out);
}

// Round 23
// 515.384 us; speedup vs baseline: 6.0657x; 1.4011x over previous
//
#include <hip/hip_runtime.h>
#include <math.h>

constexpr int T_STEPS = 32;
constexpr int BATCH   = 128;
constexpr int IN_SZ   = 2048;   // K
constexpr int OUT_SZ  = 2048;   // N

// -------------------------------------------------------------------------
// FROZEN reference arithmetic (verified r14, absmax 0.0 r15-r22):
//   GEMM: f32, KC=512 uniform K-blocks; per element a fresh ascending-k
//         fmaf chain per block, f32 sequential block-combine.
//   Scan: f64 state, un = D*u + y (sep mul/add), s = (un>=1), u = un-s,
//         D = 1/(1+exp(-2)) in f64.
// r23: occupancy-first. 64x64 tile (BB=2, m=2t+b), 128 threads, 8x4 micro
// (proven reg footprint), r16's simple 2-barrier staging, and a TWO-PHASE
// scan epilogue so the y-buffer is only 32x65 floats -> LDS 8.3 KB/block.
// Grid = 2048 blocks = 8/CU, ALL resident (16 waves/CU at VGPR<=128):
// TLP hides the load latency + barrier drain that r17-r22's pipelining
// attempts could not. Per-element chain arithmetic bit-identical.
// -------------------------------------------------------------------------
__global__ __launch_bounds__(128, 1) void Approx_OTPE_67181878444197_kernel(
        const float* __restrict__ x,
        const float* __restrict__ W,
        float* __restrict__ out) {
    constexpr int BK = 16, BM = 64, BN = 64;
    constexpr int YSTR = BN + 1;            // 65
    constexpr int YSZ  = 32 * YSTR;         // 2080 floats = 8.32 KB

    __shared__ float smem[YSZ];             // stage (2048 f) aliased with y
    float* const As = smem;                 // [BK][BM] k-major
    float* const Bs = smem + BK * BM;       // [BK][BN]

    const int o0  = blockIdx.x * BN;
    const int b0  = blockIdx.y * 2;
    const int tid = threadIdx.x;            // 0..127
    const int ty  = tid >> 4;               // 0..7  -> 8-row group
    const int tx  = tid & 15;               // 0..15 -> 4-col group

    // A staging: m_local = tid>>1 (0..63), k-half = (tid&1)*8
    // m_local = 2t + b_local
    const int am = tid >> 1;
    const int ak = (tid & 1) * 8;
    const int at = am >> 1;
    const int ab = am & 1;
    const size_t aBase = ((size_t)at * BATCH + (size_t)(b0 + ab)) * IN_SZ + ak;

    // B staging: row br (0..15), col bc (0..56), two float4 per thread
    const int br = tid >> 3;
    const int bc = (tid & 7) * 8;

    float acc[8][4] = {};   // current KC=512 chain
    float su[8][4]  = {};   // running sequential block-combine

    #pragma unroll 1
    for (int it = 0; it < IN_SZ / BK; ++it) {
        const int k0 = it * BK;
        // issue global loads at top (overlap with other blocks' compute)
        const float4 a0 = *reinterpret_cast<const float4*>(&x[aBase + k0]);
        const float4 a1 = *reinterpret_cast<const float4*>(&x[aBase + k0 + 4]);
        const float4 v0 = *reinterpret_cast<const float4*>(
            &W[(size_t)(k0 + br) * OUT_SZ + o0 + bc]);
        const float4 v1 = *reinterpret_cast<const float4*>(
            &W[(size_t)(k0 + br) * OUT_SZ + o0 + bc + 4]);

        // KC=512 boundary (k0 = 512/1024/1536): sequential combine (FROZEN)
        if (it == 32 || it == 64 || it == 96) {
            #pragma unroll
            for (int i = 0; i < 8; ++i)
                #pragma unroll
                for (int j = 0; j < 4; ++j) {
                    su[i][j]  = __fadd_rn(su[i][j], acc[i][j]);
                    acc[i][j] = 0.0f;
                }
        }

        __syncthreads();   // previous iteration's LDS reads done
        As[(ak + 0) * BM + am] = a0.x;
        As[(ak + 1) * BM + am] = a0.y;
        As[(ak + 2) * BM + am] = a0.z;
        As[(ak + 3) * BM + am] = a0.w;
        As[(ak + 4) * BM + am] = a1.x;
        As[(ak + 5) * BM + am] = a1.y;
        As[(ak + 6) * BM + am] = a1.z;
        As[(ak + 7) * BM + am] = a1.w;
        *reinterpret_cast<float4*>(&Bs[br * BN + bc])     = v0;
        *reinterpret_cast<float4*>(&Bs[br * BN + bc + 4]) = v1;
        __syncthreads();

        // ascending k; each acc[i][j] is one strict fmaf chain (FROZEN)
        #pragma unroll
        for (int k = 0; k < BK; ++k) {
            const float4 x0 = *reinterpret_cast<const float4*>(&As[k * BM + ty * 8]);
            const float4 x1 = *reinterpret_cast<const float4*>(&As[k * BM + ty * 8 + 4]);
            const float4 wf = *reinterpret_cast<const float4*>(&Bs[k * BN + tx * 4]);
            const float a[8] = {x0.x, x0.y, x0.z, x0.w, x1.x, x1.y, x1.z, x1.w};
            const float w[4] = {wf.x, wf.y, wf.z, wf.w};
            #pragma unroll
            for (int i = 0; i < 8; ++i)
                #pragma unroll
                for (int j = 0; j < 4; ++j)
                    acc[i][j] = __builtin_fmaf(a[i], w[j], acc[i][j]);
        }
    }

    // final combine (FROZEN): y = su + acc
    #pragma unroll
    for (int i = 0; i < 8; ++i)
        #pragma unroll
        for (int j = 0; j < 4; ++j)
            su[i][j] = __fadd_rn(su[i][j], acc[i][j]);

    // ---- two-phase fused f64 scan (y-LDS = 32 rows only) ----------------
    const int bl = tid >> 6;                // 0..1
    const int o  = tid & 63;                // 0..63
    const size_t plane  = (size_t)BATCH * OUT_SZ;
    const size_t outIdx = (size_t)(b0 + bl) * OUT_SZ + o0 + o;
    const double D = 1.0 / (1.0 + exp(-2.0));
    double u = 0.0;

    #pragma unroll
    for (int p = 0; p < 2; ++p) {
        __syncthreads();                    // prev phase/loop reads done
        if ((ty >> 2) == p) {               // ty 0-3 (p=0) or 4-7 (p=1)
            const int rb = ty * 8 - p * 32;
            #pragma unroll
            for (int i = 0; i < 8; ++i)
                #pragma unroll
                for (int j = 0; j < 4; ++j)
                    smem[(rb + i) * YSTR + tx * 4 + j] = su[i][j];
        }
        __syncthreads();
        #pragma unroll
        for (int tt = 0; tt < 16; ++tt) {   // local rows: m - 32p = 2*tt+bl
            const int t = p * 16 + tt;
            const double y  = (double)smem[(tt * 2 + bl) * YSTR + o];
            const double un = __dadd_rn(__dmul_rn(D, u), y);
            const double s  = (un >= 1.0) ? 1.0 : 0.0;
            u = __dsub_rn(un, s);
            out[(size_t)t * plane + outIdx] = (float)s;
        }
    }
}

// -------------------------------------------------------------------------
extern "C" void kernel_launch(void* const* d_in, const int* in_sizes, int n_in,
                              void* d_out, int out_size, void* d_ws, size_t ws_size,
                              hipStream_t stream) {
    const float* x = (const float*)d_in[0];   // [T, B, IN] f32
    const float* W = (const float*)d_in[1];   // [IN, OUT] f32
    float* out     = (float*)d_out;           // [T, B, OUT] f32 spikes

    dim3 grid(OUT_SZ / 64, BATCH / 2);        // 32 x 64 = 2048 blocks (8/CU)
    Approx_OTPE_67181878444197_kernel<<<grid, 128, 0, stream>>>(x, W, out);
}